// Round 15
// baseline (41.548 us; speedup 1.0000x reference)
//
#include <hip/hip_runtime.h>

// sites [4096,128] f32, consensus [512,128] f32
// out = softmax(-L1dist, axis=-1) -> [4096,512] f32
#define N_SITES 4096
#define M_CONS  512
#define DIM     128
#define RPB     4         // site rows per block
#define CH      8         // dims per chunk
#define NCH     16        // chunks
#define QPC     2         // 16B-quads per col per chunk (CH/4)

// Single fused kernel = R12 structure pushed to 8 waves/SIMD.
// 1024 blocks x 512 threads, 32 KB LDS (2 x 16 KB) -> 4 blocks/CU
// = 32 waves/CU = 8 waves/SIMD (grid = exactly one full residency wave).
// __launch_bounds__(512,2) pins the allocator at ~60-64 VGPR (session law);
// live state here is ~20 regs (cv[8]+d[4]+addr) so the cap is SAFE - this is
// the first structure where the hint can't cause spills.
// Lane owns consensus column col==tid (validated R9-R13): cv[8] in VGPRs;
// sites block-uniform -> s_load -> SGPR operand; inner loop pure VALU
// (v_sub + v_add with abs modifier = the f32 floor, 2 ops/dim; packed f32
// has no abs/max on gfx950 - R14).
// Staging: global_load_lds w=16, pre-swizzled global source (#21), linear
// LDS dest. 32 B column stride -> swizzle key (c>>2)&1: bank start
// 8*(c&3) + 4*(g^key) covers all 8 residues evenly -> every b128 extract
// is exactly 8 dwords/bank (the floor).
// Softmax: block-local; dmat[4][512] overlay, waves 0-3 reduce rows 0-3
// (min + expsum via shuffles), broadcast red, coalesced stores.
__global__ __launch_bounds__(512, 2) void fused_kernel(const float* __restrict__ sites,
                                                       const float* __restrict__ cons,
                                                       float* __restrict__ out) {
    __shared__ __align__(16) float lds[8192];    // 32 KB = 2 x 16 KB buffers

    const int tid = threadIdx.x;
    const int bid = blockIdx.x;
    const int r0  = bid * RPB;

    // ---- prologue: DMA chunk 0 into buffer 0 (1024 slots, 2 per thread)
#pragma unroll
    for (int c = 0; c < 2; c++) {
        const int f = c * 512 + tid;             // slot 0..1023
        const int r = f >> 1, q = f & 1;
        const float* gsrc = cons + (size_t)r * DIM + ((q ^ ((r >> 2) & 1)) << 2);
        __builtin_amdgcn_global_load_lds(
            (const __attribute__((address_space(1))) void*)gsrc,
            (__attribute__((address_space(3))) void*)&lds[f * 4], 16, 0, 0);
    }
    __syncthreads();

    float d[RPB];
#pragma unroll
    for (int i = 0; i < RPB; i++) d[i] = 0.f;

    const float* srow = sites + (size_t)r0 * DIM;
    const int key = (tid >> 2) & 1;

#pragma unroll
    for (int h = 0; h < NCH; h++) {
        float* cur = &lds[(h & 1) * 4096];       // compile-time (full unroll)
        float* nxt = &lds[((h + 1) & 1) * 4096];

        // ---- extract my column (2 x ds_read_b128, 8 dwords/bank = floor)
        float cv[CH];
#pragma unroll
        for (int g = 0; g < QPC; g++) {
            float4 v = *(const float4*)&cur[tid * CH + ((g ^ key) << 2)];
            cv[4*g+0] = v.x; cv[4*g+1] = v.y; cv[4*g+2] = v.z; cv[4*g+3] = v.w;
        }

        // ---- issue next chunk's DMA (zero register cost, lands under compute)
        if (h < NCH - 1) {
#pragma unroll
            for (int c = 0; c < 2; c++) {
                const int f = c * 512 + tid;
                const int r = f >> 1, q = f & 1;
                const float* gsrc = cons + (size_t)r * DIM + (h + 1) * CH
                                         + ((q ^ ((r >> 2) & 1)) << 2);
                __builtin_amdgcn_global_load_lds(
                    (const __attribute__((address_space(1))) void*)gsrc,
                    (__attribute__((address_space(3))) void*)&nxt[f * 4], 16, 0, 0);
            }
        }

        // ---- pure-VALU accumulation: 4 rows x 8 dims (srow -> SGPR)
#pragma unroll
        for (int rr = 0; rr < RPB; rr++) {
#pragma unroll
            for (int k = 0; k < CH; k++)
                d[rr] += fabsf(srow[rr * DIM + h * CH + k] - cv[k]);
        }

        __syncthreads();                         // drains vmcnt -> nxt ready
    }

    // ---- block-local softmax: dmat[4][512] overlay (8 KB of buffer 0)
#pragma unroll
    for (int rr = 0; rr < RPB; rr++)
        lds[rr * 512 + tid] = d[rr];             // consecutive lanes: free
    __syncthreads();

    const int wv = tid >> 6;
    const int ln = tid & 63;
    if (wv < RPB) {                              // waves 0-3 reduce rows 0-3
        const float* p = &lds[wv * 512 + ln * 8];
        float4 a = *(const float4*)(p);
        float4 b = *(const float4*)(p + 4);
        float m = fminf(fminf(fminf(a.x, a.y), fminf(a.z, a.w)),
                        fminf(fminf(b.x, b.y), fminf(b.z, b.w)));
#pragma unroll
        for (int off = 32; off > 0; off >>= 1) m = fminf(m, __shfl_xor(m, off));
        float s = ((__expf(m - a.x) + __expf(m - a.y)) + (__expf(m - a.z) + __expf(m - a.w)))
                + ((__expf(m - b.x) + __expf(m - b.y)) + (__expf(m - b.z) + __expf(m - b.w)));
#pragma unroll
        for (int off = 32; off > 0; off >>= 1) s += __shfl_xor(s, off);
        if (ln == 0) {
            lds[2048 + wv] = m;                  // row min  [4]
            lds[2056 + wv] = 1.f / s;            // row inv-sum [4]
        }
    }
    __syncthreads();

    // ---- final: exp(mn - d) * inv from registers, coalesced 2 KB stores
#pragma unroll
    for (int rr = 0; rr < RPB; rr++) {
        float mn  = lds[2048 + rr];              // broadcast (same address)
        float inv = lds[2056 + rr];
        out[(size_t)(r0 + rr) * M_CONS + tid] = __expf(mn - d[rr]) * inv;
    }
}

extern "C" void kernel_launch(void* const* d_in, const int* in_sizes, int n_in,
                              void* d_out, int out_size, void* d_ws, size_t ws_size,
                              hipStream_t stream) {
    const float* sites = (const float*)d_in[0];
    const float* cons  = (const float*)d_in[1];
    float* out = (float*)d_out;

    fused_kernel<<<N_SITES / RPB, 512, 0, stream>>>(sites, cons, out);  // 1024 blocks
}

// Round 16
// 21.472 us; speedup vs baseline: 1.9349x; 1.9349x over previous
//
#include <hip/hip_runtime.h>

// sites [4096,128] f32, consensus [512,128] f32
// out = softmax(-L1dist, axis=-1) -> [4096,512] f32
#define N_SITES 4096
#define M_CONS  512
#define DIM     128
#define RPB     8         // site rows per block
#define CH      16        // dims per chunk
#define NCH     8         // chunks
#define QPC     4         // 16B-quads per col per chunk (CH/4)

// Single fused kernel = R12 (best, 21.26 us) + BLOCK-PARITY PHASE ROTATION:
// odd blocks process chunks in order 4,5,..,7,0,..,3 so the two co-resident
// blocks on each CU hit their stall points (extract lgkm waits, s_load
// waits, barrier drains) 4 chunks apart instead of in lockstep -> the CU
// VALU stays fed by one block while the other waits (m114 overlap needs
// phase diversity). d-sum is merely reordered (f32 rounding << 2e-2 budget).
//
// Geometry (validated R12): 512 blocks x 512 threads, 64 KB LDS (2x32 KB)
// -> 2 blocks/CU = 4 waves/SIMD; __launch_bounds__(512,1) -> 88 VGPR, no
// spill (any min-waves>=2 hint breaks the allocator - R6/7/8/10/15).
// Lane owns consensus column col==tid: cv[16] in VGPRs; sites block-uniform
// -> s_load -> SGPR operand; inner loop pure VALU (2 ops/dim = f32 floor).
// Staging: global_load_lds w=16, pre-swizzled global source (#21), linear
// LDS dest; swizzle key ((r>>1)&3) spreads extract reads across banks.
// Softmax: block-local; dmat[8][512] overlay, wave-per-row shuffle reduce.
__global__ __launch_bounds__(512, 1) void fused_kernel(const float* __restrict__ sites,
                                                       const float* __restrict__ cons,
                                                       float* __restrict__ out) {
    __shared__ __align__(16) float lds[16384];   // 64 KB = 2 x 32 KB buffers

    const int tid = threadIdx.x;
    const int bid = blockIdx.x;
    const int r0  = bid * RPB;
    const int off = (bid & 1) * 4;               // phase rotation (0 or 4)

    // ---- prologue: DMA chunk `off` into buffer 0 (2048 slots, 4/thread)
#pragma unroll
    for (int c = 0; c < 4; c++) {
        const int f = c * 512 + tid;             // slot 0..2047
        const int r = f >> 2, q = f & 3;
        const float* gsrc = cons + (size_t)r * DIM + off * CH
                                 + ((q ^ ((r >> 1) & 3)) << 2);
        __builtin_amdgcn_global_load_lds(
            (const __attribute__((address_space(1))) void*)gsrc,
            (__attribute__((address_space(3))) void*)&lds[f * 4], 16, 0, 0);
    }
    __syncthreads();

    float d[RPB];
#pragma unroll
    for (int i = 0; i < RPB; i++) d[i] = 0.f;

    const float* srow = sites + (size_t)r0 * DIM;

#pragma unroll
    for (int h = 0; h < NCH; h++) {
        const int hc = (h + off) & 7;            // this block's chunk id
        const int hn = (hc + 1) & 7;             // next chunk id
        float* cur = &lds[(h & 1) * 8192];       // buffer parity by loop index
        float* nxt = &lds[((h + 1) & 1) * 8192];

        // ---- extract my column (4 x ds_read_b128, full-bank spread)
        float cv[CH];
#pragma unroll
        for (int g = 0; g < QPC; g++) {
            float4 v = *(const float4*)&cur[tid * CH + ((g ^ ((tid >> 1) & 3)) << 2)];
            cv[4*g+0] = v.x; cv[4*g+1] = v.y; cv[4*g+2] = v.z; cv[4*g+3] = v.w;
        }

        // ---- issue next chunk's DMA (zero register cost, lands under compute)
        if (h < NCH - 1) {
#pragma unroll
            for (int c = 0; c < 4; c++) {
                const int f = c * 512 + tid;
                const int r = f >> 2, q = f & 3;
                const float* gsrc = cons + (size_t)r * DIM + hn * CH
                                         + ((q ^ ((r >> 1) & 3)) << 2);
                __builtin_amdgcn_global_load_lds(
                    (const __attribute__((address_space(1))) void*)gsrc,
                    (__attribute__((address_space(3))) void*)&nxt[f * 4], 16, 0, 0);
            }
        }

        // ---- pure-VALU accumulation: 8 rows x 16 dims (srow -> SGPR)
#pragma unroll
        for (int rr = 0; rr < RPB; rr++) {
#pragma unroll
            for (int k = 0; k < CH; k++)
                d[rr] += fabsf(srow[rr * DIM + hc * CH + k] - cv[k]);
        }

        __syncthreads();                         // drains vmcnt -> nxt ready
    }

    // ---- block-local softmax: dmat[8][512] overlay (16 KB of buffer 0)
#pragma unroll
    for (int rr = 0; rr < RPB; rr++)
        lds[rr * 512 + tid] = d[rr];             // consecutive lanes: free
    __syncthreads();

    const int wv = tid >> 6;                     // wave wv reduces row wv
    const int ln = tid & 63;
    {
        const float* p = &lds[wv * 512 + ln * 8];
        float4 a = *(const float4*)(p);
        float4 b = *(const float4*)(p + 4);
        float m = fminf(fminf(fminf(a.x, a.y), fminf(a.z, a.w)),
                        fminf(fminf(b.x, b.y), fminf(b.z, b.w)));
#pragma unroll
        for (int off2 = 32; off2 > 0; off2 >>= 1) m = fminf(m, __shfl_xor(m, off2));
        float s = ((__expf(m - a.x) + __expf(m - a.y)) + (__expf(m - a.z) + __expf(m - a.w)))
                + ((__expf(m - b.x) + __expf(m - b.y)) + (__expf(m - b.z) + __expf(m - b.w)));
#pragma unroll
        for (int off2 = 32; off2 > 0; off2 >>= 1) s += __shfl_xor(s, off2);
        if (ln == 0) {
            lds[4096 + wv] = m;                  // row min
            lds[4104 + wv] = 1.f / s;            // row inv-sum
        }
    }
    __syncthreads();

    // ---- final: exp(mn - d) * inv from registers, coalesced 2 KB stores
#pragma unroll
    for (int rr = 0; rr < RPB; rr++) {
        float mn  = lds[4096 + rr];              // broadcast (same address)
        float inv = lds[4104 + rr];
        out[(size_t)(r0 + rr) * M_CONS + tid] = __expf(mn - d[rr]) * inv;
    }
}

extern "C" void kernel_launch(void* const* d_in, const int* in_sizes, int n_in,
                              void* d_out, int out_size, void* d_ws, size_t ws_size,
                              hipStream_t stream) {
    const float* sites = (const float*)d_in[0];
    const float* cons  = (const float*)d_in[1];
    float* out = (float*)d_out;

    fused_kernel<<<N_SITES / RPB, 512, 0, stream>>>(sites, cons, out);  // 512 blocks
}